// Round 10
// baseline (119.450 us; speedup 1.0000x reference)
//
#include <hip/hip_runtime.h>
#include <hip/hip_bf16.h>
#include <stdint.h>

// B=16, T=2048, E=1024, H=128
typedef __attribute__((ext_vector_type(8))) short bf16x8;
typedef __attribute__((ext_vector_type(16))) float f32x16;
typedef __attribute__((ext_vector_type(4))) float f32x4;

__device__ __forceinline__ uint32_t cvt_pk_bf16(float a, float b){
  uint32_t r;
  asm volatile("v_cvt_pk_bf16_f32 %0, %1, %2" : "=v"(r) : "v"(a), "v"(b));
  return r;
}
__device__ __forceinline__ void permswap32(uint32_t &a, uint32_t &b){
  asm volatile("v_permlane32_swap_b32 %0, %1" : "+v"(a), "+v"(b));
}
__device__ __forceinline__ unsigned short f2bf(float f){
  uint32_t u = __float_as_uint(f);
  u += 0x7fff + ((u >> 16) & 1);   // RNE
  return (unsigned short)(u >> 16);
}

// Layouts:
//  Wt lane-linear fragment-major: frag = (k>>5)*24 + (n>>4) (n=mat*128+h, k=e).
//    interior: elem at lane*8 + (k&7), lane = (n&15) + (((k&31)>>3)<<4).
//  QK: elem(b,t,h) -> (b*64 + t/32)*4096 + (h/16)*512 + (t%32)*16 + (h%16)
//  V : elem(b,s,h) -> ((b*64 + s/32)*4 + h/32)*1024 + ((s/16)%2)*512 + (h%32)*16 + (s%16)

// ---------------- Kernel 1: W -> Wt bf16 lane-linear fragment-major
__global__ void prep_w(const float* __restrict__ Wk, const float* __restrict__ Wq,
                       const float* __restrict__ Wv, unsigned short* __restrict__ Wt){
  int idx = blockIdx.x * 256 + threadIdx.x;       // 0 .. 393215  (= dest address)
  int frag = idx >> 9;         // 0..767 = kq*24 + nq
  int r    = idx & 511;
  int ln   = r >> 3;           // lane 0..63
  int j    = r & 7;
  int kq = frag / 24;          // 0..31
  int nq = frag - kq * 24;     // 0..23
  int n  = nq * 16 + (ln & 15);          // 0..383
  int e  = kq * 32 + (ln >> 4) * 8 + j;  // 0..1023
  int mat = n >> 7;
  int h   = n & 127;
  const float* src = (mat == 0) ? Wq : (mat == 1) ? Wk : Wv;
  float v = src[e * 128 + h];
  if (mat == 0) v *= (1.4426950408889634f * 0.08838834764831845f); // log2e/sqrt(128)
  Wt[idx] = f2bf(v);
}

// ---------------- Kernel 2: fused QKV projection GEMM — attn-style.
// NO LDS, NO barriers. Each wave independent: 64 rows x 96 cols.
// Per k-step: 8 float4 A loads + 6 x 1KB B loads (batched, one waitcnt via
// compiler), 16 cvt_pk, 24 MFMA. Block = 4 waves sharing rows (A loads L1-hit).
// Grid 512 = 2 blocks/CU = 8 waves/CU; waves cover latency, no barrier coupling.
__global__ __launch_bounds__(256, 2) void proj_gemm(
    const float* __restrict__ x, const unsigned short* __restrict__ Wt,
    unsigned short* __restrict__ Qb, unsigned short* __restrict__ Kb,
    unsigned short* __restrict__ Vt){
  const int tid  = threadIdx.x;
  const int lane = tid & 63;
  const int w    = tid >> 6;            // wave 0..3 = column group (96 cols)
  const int m0   = blockIdx.x * 64;     // token-tile base (flat M=32768)

  f32x4 acc[4][6];
  #pragma unroll
  for (int i = 0; i < 4; ++i)
    #pragma unroll
    for (int jj = 0; jj < 6; ++jj) acc[i][jj] = (f32x4){0.f, 0.f, 0.f, 0.f};

  // A: lane covers row m0 + am*16 + (lane&15), k = ks*32 + (lane>>4)*8 + {0..7}
  const float* asrc = x + (size_t)(m0 + (lane & 15)) * 1024 + ((lane >> 4) << 3);
  // B: lane reads 16B at lane*8 within each 512-elem fragment
  const unsigned short* bsrc = Wt + (size_t)lane * 8;

  union BU { uint32_t u[4]; bf16x8 v; };

  for (int ks = 0; ks < 32; ++ks){
    // ---- batched loads (same-iteration use: compiler emits back-to-back) ----
    float4 ar[8];
    #pragma unroll
    for (int am = 0; am < 4; ++am){
      ar[am * 2 + 0] = *(const float4*)(asrc + am * 16384 + ks * 32);
      ar[am * 2 + 1] = *(const float4*)(asrc + am * 16384 + ks * 32 + 4);
    }
    bf16x8 bfr[6];
    #pragma unroll
    for (int bn = 0; bn < 6; ++bn)
      bfr[bn] = *(const bf16x8*)(bsrc + ((size_t)(ks * 24 + w * 6 + bn) << 9));
    // ---- convert A to bf16 fragments ----
    bf16x8 af[4];
    #pragma unroll
    for (int am = 0; am < 4; ++am){
      float4 lo = ar[am * 2 + 0], hi = ar[am * 2 + 1];
      BU u; u.u[0] = cvt_pk_bf16(lo.x, lo.y); u.u[1] = cvt_pk_bf16(lo.z, lo.w);
            u.u[2] = cvt_pk_bf16(hi.x, hi.y); u.u[3] = cvt_pk_bf16(hi.z, hi.w);
      af[am] = u.v;
    }
    // ---- 24 MFMAs ----
    #pragma unroll
    for (int am = 0; am < 4; ++am)
      #pragma unroll
      for (int bn = 0; bn < 6; ++bn)
        acc[am][bn] = __builtin_amdgcn_mfma_f32_16x16x32_bf16(af[am], bfr[bn], acc[am][bn], 0, 0, 0);
  }

  const int b  = m0 >> 11;
  const int t0 = m0 & 2047;
  const int lr = lane & 15;
  const int lk = lane >> 4;
  #pragma unroll
  for (int am = 0; am < 4; ++am){
    #pragma unroll
    for (int bn = 0; bn < 6; ++bn){
      int c0   = w * 96 + bn * 16;
      int mat  = c0 >> 7;
      int hcol = (c0 & 127) + lr;
      int tr   = t0 + am * 16 + lk * 4;    // D: row=(lane>>4)*4+j, col=lane&15
      f32x4 v = acc[am][bn];
      if (mat <= 1){
        unsigned short* dst = (mat == 0) ? Qb : Kb;
        size_t base = (size_t)(b * 64 + (tr >> 5)) * 4096 + (size_t)(hcol >> 4) * 512 + (hcol & 15);
        #pragma unroll
        for (int jj = 0; jj < 4; ++jj)
          dst[base + (size_t)((tr + jj) & 31) * 16] = f2bf(v[jj]);
      } else { // V fragment-major: 4 consecutive s -> 8B store
        ushort4 pk;
        pk.x = f2bf(v[0]); pk.y = f2bf(v[1]); pk.z = f2bf(v[2]); pk.w = f2bf(v[3]);
        size_t addr = (size_t)((b * 64 + (tr >> 5)) * 4 + (hcol >> 5)) * 1024
                    + (size_t)((tr >> 4) & 1) * 512 + (size_t)(hcol & 31) * 16 + (tr & 15);
        *(ushort4*)(Vt + addr) = pk;
      }
    }
  }
}

// ---------------- Kernel 3: causal flash attention, swapped-QK 32x32x16.
// 1024 blocks, 4 waves = 4-way kv split, scale-then-sum combine (17.9KB LDS).
__global__ __launch_bounds__(256, 2) void attn(
    const unsigned short* __restrict__ Qf, const unsigned short* __restrict__ Kf,
    const unsigned short* __restrict__ Vf, float* __restrict__ out){
  __shared__ float comb[32][132];
  __shared__ float msh[4][32];
  __shared__ float lsh[4][32];

  const int tid  = threadIdx.x;
  const int lane = tid & 63;
  const int w    = tid >> 6;            // kv-split index 0..3
  const int bid  = blockIdx.x;
  const int xcd  = bid & 7;
  const int k    = bid >> 3;            // 0..127 within XCD
  const int a    = k & 31;
  const int mdx  = k >> 5;              // 0..3
  const int b    = xcd * 2 + (mdx >> 1);
  const int c    = (mdx & 1) ? a : 63 - a;   // per-CU sets {63-a, a} x 2 batches
  const int r0   = c * 32;
  const int q5   = lane & 31;
  const int hi   = lane >> 5;

  bf16x8 qf[8];
  const unsigned short* qp = Qf + (size_t)(b * 64 + c) * 4096 + q5 * 16 + hi * 8;
  #pragma unroll
  for (int f = 0; f < 8; ++f) qf[f] = *(const bf16x8*)(qp + f * 512);

  f32x16 oacc[4];
  #pragma unroll
  for (int i = 0; i < 4; ++i) oacc[i] = (f32x16)(0.f);
  float m = -1e30f, l = 0.f;

  const unsigned short* kb = Kf + (size_t)b * 64 * 4096;
  const unsigned short* vb = Vf + (size_t)b * 64 * 4096;

  bf16x8 kf[8];
  if (w <= c){
    const unsigned short* kp = kb + (size_t)w * 4096 + q5 * 16 + hi * 8;
    #pragma unroll
    for (int f = 0; f < 8; ++f) kf[f] = *(const bf16x8*)(kp + f * 512);
  }

  for (int t = w; t <= c; t += 4){
    f32x16 sacc = (f32x16)(0.f);   // S^T[s][q] = sum_h K[s][h] Q[q][h]
    #pragma unroll
    for (int f = 0; f < 8; ++f)
      sacc = __builtin_amdgcn_mfma_f32_32x32x16_bf16(kf[f], qf[f], sacc, 0, 0, 0);
    // prefetch next K tile (overlaps softmax+PV)
    if (t + 4 <= c){
      const unsigned short* kp = kb + (size_t)(t + 4) * 4096 + q5 * 16 + hi * 8;
      #pragma unroll
      for (int f = 0; f < 8; ++f) kf[f] = *(const bf16x8*)(kp + f * 512);
    }
    // V fragments (contiguous 1KB per instr), issued before softmax
    bf16x8 vf[8];
    const unsigned short* vp = vb + (size_t)t * 4096 + q5 * 16 + hi * 8;
    #pragma unroll
    for (int ht = 0; ht < 4; ++ht)
      #pragma unroll
      for (int sf = 0; sf < 2; ++sf)
        vf[ht * 2 + sf] = *(const bf16x8*)(vp + ht * 1024 + sf * 512);

    float sv[16];
    #pragma unroll
    for (int r = 0; r < 16; ++r) sv[r] = sacc[r];
    if (t == c){   // diagonal tile: mask s>q  (row = (r&3)+8*(r>>2)+4*hi, col q = q5)
      #pragma unroll
      for (int r = 0; r < 16; ++r){
        int srow = (r & 3) + 8 * (r >> 2) + 4 * hi;
        if (srow > q5) sv[r] = -1e30f;
      }
    }
    float pm = sv[0];
    #pragma unroll
    for (int r = 1; r < 16; ++r) pm = fmaxf(pm, sv[r]);
    pm = fmaxf(pm, __shfl_xor(pm, 32));
    if (!__all(pm - m <= 8.0f)){   // defer-max (log2 domain)
      float mn = fmaxf(m, pm);
      float al = exp2f(m - mn);
      #pragma unroll
      for (int i = 0; i < 4; ++i) oacc[i] *= al;
      l *= al;
      m = mn;
    }
    float pv[16]; float ts = 0.f;
    #pragma unroll
    for (int r = 0; r < 16; ++r){ pv[r] = exp2f(sv[r] - m); ts += pv[r]; }
    ts += __shfl_xor(ts, 32);
    l += ts;
    // P^T -> bf16 B-frags: cvt_pk + permlane32_swap (fills both k-halves)
    uint32_t w0 = cvt_pk_bf16(pv[0],  pv[1]);
    uint32_t w2 = cvt_pk_bf16(pv[4],  pv[5]);  permswap32(w0, w2);
    uint32_t w1 = cvt_pk_bf16(pv[2],  pv[3]);
    uint32_t w3 = cvt_pk_bf16(pv[6],  pv[7]);  permswap32(w1, w3);
    uint32_t w4 = cvt_pk_bf16(pv[8],  pv[9]);
    uint32_t w6 = cvt_pk_bf16(pv[12], pv[13]); permswap32(w4, w6);
    uint32_t w5 = cvt_pk_bf16(pv[10], pv[11]);
    uint32_t w7 = cvt_pk_bf16(pv[14], pv[15]); permswap32(w5, w7);
    union { uint32_t u[4]; bf16x8 v; } pf0u, pf1u;
    pf0u.u[0] = w0; pf0u.u[1] = w1; pf0u.u[2] = w2; pf0u.u[3] = w3;
    pf1u.u[0] = w4; pf1u.u[1] = w5; pf1u.u[2] = w6; pf1u.u[3] = w7;
    #pragma unroll
    for (int ht = 0; ht < 4; ++ht){   // O^T[h][q] += V^T · P^T
      oacc[ht] = __builtin_amdgcn_mfma_f32_32x32x16_bf16(vf[ht * 2 + 0], pf0u.v, oacc[ht], 0, 0, 0);
      oacc[ht] = __builtin_amdgcn_mfma_f32_32x32x16_bf16(vf[ht * 2 + 1], pf1u.v, oacc[ht], 0, 0, 0);
    }
  }

  // -------- scale-then-sum combine --------
  if (hi == 0){ msh[w][q5] = m; lsh[w][q5] = l; }
  __syncthreads();
  {
    float mv0 = msh[0][q5], mv1 = msh[1][q5], mv2 = msh[2][q5], mv3 = msh[3][q5];
    float lv0 = lsh[0][q5], lv1 = lsh[1][q5], lv2 = lsh[2][q5], lv3 = lsh[3][q5];
    float mfm = fmaxf(fmaxf(mv0, mv1), fmaxf(mv2, mv3));
    float lf  = lv0 * exp2f(mv0 - mfm) + lv1 * exp2f(mv1 - mfm)
              + lv2 * exp2f(mv2 - mfm) + lv3 * exp2f(mv3 - mfm);
    float s = exp2f(m - mfm) / lf;
    #pragma unroll
    for (int ht = 0; ht < 4; ++ht) oacc[ht] *= s;
  }
  // serial RMW accumulate into comb (wave 0 writes, 1..3 add)
  #pragma unroll 1
  for (int rr = 0; rr < 4; ++rr){
    if (w == rr){
      #pragma unroll
      for (int ht = 0; ht < 4; ++ht)
        #pragma unroll
        for (int r4 = 0; r4 < 4; ++r4){
          int hh = ht * 32 + 8 * r4 + 4 * hi;
          float4 add;
          add.x = oacc[ht][r4 * 4 + 0]; add.y = oacc[ht][r4 * 4 + 1];
          add.z = oacc[ht][r4 * 4 + 2]; add.w = oacc[ht][r4 * 4 + 3];
          float* p = &comb[q5][hh];
          if (rr == 0) *(float4*)p = add;
          else { float4 cur = *(const float4*)p;
                 cur.x += add.x; cur.y += add.y; cur.z += add.z; cur.w += add.w;
                 *(float4*)p = cur; }
        }
    }
    __syncthreads();
  }
  // cooperative coalesced store: 32 rows x 128 f32
  float* obase = out + ((size_t)b * 2048 + r0) * 128;
  #pragma unroll
  for (int it = 0; it < 4; ++it){
    int row = it * 8 + (tid >> 5);
    int col = (tid & 31) * 4;
    *(float4*)(obase + row * 128 + col) = *(const float4*)&comb[row][col];
  }
}

extern "C" void kernel_launch(void* const* d_in, const int* in_sizes, int n_in,
                              void* d_out, int out_size, void* d_ws, size_t ws_size,
                              hipStream_t stream){
  const float* x  = (const float*)d_in[0];
  // d_in[1] = mask : causal tril by construction, applied structurally
  const float* Wk = (const float*)d_in[2];
  const float* Wq = (const float*)d_in[3];
  const float* Wv = (const float*)d_in[4];
  char* ws = (char*)d_ws;
  unsigned short* Wt = (unsigned short*)(ws);                    // 768 KB
  unsigned short* Qb = (unsigned short*)(ws + (1ull  << 20));    // 8 MB
  unsigned short* Kb = (unsigned short*)(ws + (9ull  << 20));    // 8 MB
  unsigned short* Vt = (unsigned short*)(ws + (17ull << 20));    // 8 MB
  float* out = (float*)d_out;

  hipLaunchKernelGGL(prep_w,    dim3(1536), dim3(256), 0, stream, Wk, Wq, Wv, Wt);
  hipLaunchKernelGGL(proj_gemm, dim3(512),  dim3(256), 0, stream, x, Wt, Qb, Kb, Vt);
  hipLaunchKernelGGL(attn,      dim3(1024), dim3(256), 0, stream, Qb, Kb, Vt, out);
}

// Round 11
// 113.036 us; speedup vs baseline: 1.0567x; 1.0567x over previous
//
#include <hip/hip_runtime.h>
#include <hip/hip_bf16.h>
#include <stdint.h>

// B=16, T=2048, E=1024, H=128
typedef __attribute__((ext_vector_type(8))) short bf16x8;
typedef __attribute__((ext_vector_type(16))) float f32x16;
typedef __attribute__((ext_vector_type(4))) float f32x4;

__device__ __forceinline__ uint32_t cvt_pk_bf16(float a, float b){
  uint32_t r;
  asm volatile("v_cvt_pk_bf16_f32 %0, %1, %2" : "=v"(r) : "v"(a), "v"(b));
  return r;
}
__device__ __forceinline__ void permswap32(uint32_t &a, uint32_t &b){
  asm volatile("v_permlane32_swap_b32 %0, %1" : "+v"(a), "+v"(b));
}
__device__ __forceinline__ unsigned short f2bf(float f){
  uint32_t u = __float_as_uint(f);
  u += 0x7fff + ((u >> 16) & 1);   // RNE
  return (unsigned short)(u >> 16);
}
__device__ __forceinline__ void gload16(const void* g, void* l){
  __builtin_amdgcn_global_load_lds((const __attribute__((address_space(1))) void*)g,
                                   (__attribute__((address_space(3))) void*)l, 16, 0, 0);
}

// Layouts:
//  Wt lane-linear fragment-major: frag = (k>>5)*24 + (n>>4) (n=mat*128+h, k=e).
//    interior: elem at lane*8 + (k&7), lane = (n&15) + (((k&31)>>3)<<4).
//  QK: elem(b,t,h) -> (b*64 + t/32)*4096 + (h/16)*512 + (t%32)*16 + (h%16)
//  V : elem(b,s,h) -> ((b*64 + s/32)*4 + h/32)*1024 + ((s/16)%2)*512 + (h%32)*16 + (s%16)

// ---------------- Kernel 1: W -> Wt bf16 lane-linear fragment-major
__global__ void prep_w(const float* __restrict__ Wk, const float* __restrict__ Wq,
                       const float* __restrict__ Wv, unsigned short* __restrict__ Wt){
  int idx = blockIdx.x * 256 + threadIdx.x;       // 0 .. 393215  (= dest address)
  int frag = idx >> 9;         // 0..767 = kq*24 + nq
  int r    = idx & 511;
  int ln   = r >> 3;           // lane 0..63
  int j    = r & 7;
  int kq = frag / 24;          // 0..31
  int nq = frag - kq * 24;     // 0..23
  int n  = nq * 16 + (ln & 15);          // 0..383
  int e  = kq * 32 + (ln >> 4) * 8 + j;  // 0..1023
  int mat = n >> 7;
  int h   = n & 127;
  const float* src = (mat == 0) ? Wq : (mat == 1) ? Wk : Wv;
  float v = src[e * 128 + h];
  if (mat == 0) v *= (1.4426950408889634f * 0.08838834764831845f); // log2e/sqrt(128)
  Wt[idx] = f2bf(v);
}

// ---------------- Kernel 2: fused QKV projection GEMM — faithful m97 clone.
// Tile 128x128, BK=32, grid 768 (256 mt x 3 nt) = 3 blocks/CU; 4 waves, each 64x64
// (4x4 f32x4 acc). LDS 24KB single-buffered: As[8 frags][2 halves][64 lanes][4]f32,
// Bs[8 frags][64 lanes][8]bf16 — every gload16 dest is a wave-uniform 1KB chunk with
// lane*16B interior; every ds_read_b128 is lane*16B (conflict-free). Two plain
// __syncthreads per k-step; 3 co-resident blocks/CU cover the vmcnt drain (m114).
__global__ __launch_bounds__(256, 3) void proj_gemm(
    const float* __restrict__ x, const unsigned short* __restrict__ Wt,
    unsigned short* __restrict__ Qb, unsigned short* __restrict__ Kb,
    unsigned short* __restrict__ Vt){
  __shared__ __align__(16) float          As[8][2][64][4];  // 16 KB
  __shared__ __align__(16) unsigned short Bs[8][64][8];     // 8 KB

  const int tid  = threadIdx.x;
  const int lane = tid & 63;
  const int w    = tid >> 6;            // wave 0..3
  const int wr   = w >> 1;              // row half (64 rows)
  const int wc   = w & 1;               // col half (64 cols)
  const int bid  = blockIdx.x;
  const int mt   = bid / 3;
  const int nt   = bid - mt * 3;        // 0..2 -> exactly one of Q/K/V
  const int m0   = mt * 128;

  f32x4 acc[4][4];
  #pragma unroll
  for (int i = 0; i < 4; ++i)
    #pragma unroll
    for (int jj = 0; jj < 4; ++jj) acc[i][jj] = (f32x4){0.f, 0.f, 0.f, 0.f};

  // A staging: wave w stages chunks c=0..3 -> frag f=w*2+(c>>1), half h=c&1.
  // lane l sources 16B: x[(m0 + f*16 + (l&15))*1024 + ks*32 + (l>>4)*8 + h*4]
  const float* aA[4];
  #pragma unroll
  for (int c = 0; c < 4; ++c){
    int f = w * 2 + (c >> 1), h = c & 1;
    aA[c] = x + (size_t)(m0 + f * 16 + (lane & 15)) * 1024 + ((lane >> 4) << 3) + h * 4;
  }
  // B staging: wave w stages frags f=w*2+c (c=0..1); lane sources 16B at frag*512+l*8.
  const unsigned short* bA[2];
  #pragma unroll
  for (int c = 0; c < 2; ++c)
    bA[c] = Wt + ((size_t)(nt * 8 + w * 2 + c) << 9) + (size_t)lane * 8;

  union BU { uint32_t u[4]; bf16x8 v; };

  for (int ks = 0; ks < 32; ++ks){
    // stage current k-slice (6 x gload16 per wave, wave-uniform 1KB dests)
    #pragma unroll
    for (int c = 0; c < 4; ++c)
      gload16(aA[c] + ks * 32, &As[w * 2 + (c >> 1)][c & 1][0][0]);
    #pragma unroll
    for (int c = 0; c < 2; ++c)
      gload16(bA[c] + (size_t)ks * 12288, &Bs[w * 2 + c][0][0]);
    __syncthreads();   // drain vmcnt -> LDS valid

    bf16x8 af[4];
    #pragma unroll
    for (int am = 0; am < 4; ++am){
      float4 lo = *(const float4*)&As[wr * 4 + am][0][lane][0];
      float4 hi = *(const float4*)&As[wr * 4 + am][1][lane][0];
      BU u; u.u[0] = cvt_pk_bf16(lo.x, lo.y); u.u[1] = cvt_pk_bf16(lo.z, lo.w);
            u.u[2] = cvt_pk_bf16(hi.x, hi.y); u.u[3] = cvt_pk_bf16(hi.z, hi.w);
      af[am] = u.v;
    }
    bf16x8 bfr[4];
    #pragma unroll
    for (int bn = 0; bn < 4; ++bn)
      bfr[bn] = *(const bf16x8*)&Bs[wc * 4 + bn][lane][0];
    #pragma unroll
    for (int am = 0; am < 4; ++am)
      #pragma unroll
      for (int bn = 0; bn < 4; ++bn)
        acc[am][bn] = __builtin_amdgcn_mfma_f32_16x16x32_bf16(af[am], bfr[bn], acc[am][bn], 0, 0, 0);
    __syncthreads();   // reads done before next stage overwrites
  }

  const int b  = m0 >> 11;
  const int t0 = m0 & 2047;
  const int lr = lane & 15;
  const int lk = lane >> 4;
  #pragma unroll
  for (int am = 0; am < 4; ++am){
    #pragma unroll
    for (int bn = 0; bn < 4; ++bn){
      int hcol = wc * 64 + bn * 16 + lr;            // 0..127 within matrix nt
      int tr   = t0 + wr * 64 + am * 16 + lk * 4;   // D: row=(lane>>4)*4+j, col=lane&15
      f32x4 v = acc[am][bn];
      if (nt <= 1){
        unsigned short* dst = (nt == 0) ? Qb : Kb;
        size_t base = (size_t)(b * 64 + (tr >> 5)) * 4096 + (size_t)(hcol >> 4) * 512 + (hcol & 15);
        #pragma unroll
        for (int jj = 0; jj < 4; ++jj)
          dst[base + (size_t)((tr + jj) & 31) * 16] = f2bf(v[jj]);
      } else { // V fragment-major: 4 consecutive s -> 8B store
        ushort4 pk;
        pk.x = f2bf(v[0]); pk.y = f2bf(v[1]); pk.z = f2bf(v[2]); pk.w = f2bf(v[3]);
        size_t addr = (size_t)((b * 64 + (tr >> 5)) * 4 + (hcol >> 5)) * 1024
                    + (size_t)((tr >> 4) & 1) * 512 + (size_t)(hcol & 31) * 16 + (tr & 15);
        *(ushort4*)(Vt + addr) = pk;
      }
    }
  }
}

// ---------------- Kernel 3: causal flash attention, swapped-QK 32x32x16.
// 1024 blocks, 4 waves = 4-way kv split, scale-then-sum combine (17.9KB LDS).
__global__ __launch_bounds__(256, 2) void attn(
    const unsigned short* __restrict__ Qf, const unsigned short* __restrict__ Kf,
    const unsigned short* __restrict__ Vf, float* __restrict__ out){
  __shared__ float comb[32][132];
  __shared__ float msh[4][32];
  __shared__ float lsh[4][32];

  const int tid  = threadIdx.x;
  const int lane = tid & 63;
  const int w    = tid >> 6;            // kv-split index 0..3
  const int bid  = blockIdx.x;
  const int xcd  = bid & 7;
  const int k    = bid >> 3;            // 0..127 within XCD
  const int a    = k & 31;
  const int mdx  = k >> 5;              // 0..3
  const int b    = xcd * 2 + (mdx >> 1);
  const int c    = (mdx & 1) ? a : 63 - a;   // per-CU sets {63-a, a} x 2 batches
  const int r0   = c * 32;
  const int q5   = lane & 31;
  const int hi   = lane >> 5;

  bf16x8 qf[8];
  const unsigned short* qp = Qf + (size_t)(b * 64 + c) * 4096 + q5 * 16 + hi * 8;
  #pragma unroll
  for (int f = 0; f < 8; ++f) qf[f] = *(const bf16x8*)(qp + f * 512);

  f32x16 oacc[4];
  #pragma unroll
  for (int i = 0; i < 4; ++i) oacc[i] = (f32x16)(0.f);
  float m = -1e30f, l = 0.f;

  const unsigned short* kb = Kf + (size_t)b * 64 * 4096;
  const unsigned short* vb = Vf + (size_t)b * 64 * 4096;

  bf16x8 kf[8];
  if (w <= c){
    const unsigned short* kp = kb + (size_t)w * 4096 + q5 * 16 + hi * 8;
    #pragma unroll
    for (int f = 0; f < 8; ++f) kf[f] = *(const bf16x8*)(kp + f * 512);
  }

  for (int t = w; t <= c; t += 4){
    f32x16 sacc = (f32x16)(0.f);   // S^T[s][q] = sum_h K[s][h] Q[q][h]
    #pragma unroll
    for (int f = 0; f < 8; ++f)
      sacc = __builtin_amdgcn_mfma_f32_32x32x16_bf16(kf[f], qf[f], sacc, 0, 0, 0);
    // prefetch next K tile (overlaps softmax+PV)
    if (t + 4 <= c){
      const unsigned short* kp = kb + (size_t)(t + 4) * 4096 + q5 * 16 + hi * 8;
      #pragma unroll
      for (int f = 0; f < 8; ++f) kf[f] = *(const bf16x8*)(kp + f * 512);
    }
    // V fragments (contiguous 1KB per instr), issued before softmax
    bf16x8 vf[8];
    const unsigned short* vp = vb + (size_t)t * 4096 + q5 * 16 + hi * 8;
    #pragma unroll
    for (int ht = 0; ht < 4; ++ht)
      #pragma unroll
      for (int sf = 0; sf < 2; ++sf)
        vf[ht * 2 + sf] = *(const bf16x8*)(vp + ht * 1024 + sf * 512);

    float sv[16];
    #pragma unroll
    for (int r = 0; r < 16; ++r) sv[r] = sacc[r];
    if (t == c){   // diagonal tile: mask s>q  (row = (r&3)+8*(r>>2)+4*hi, col q = q5)
      #pragma unroll
      for (int r = 0; r < 16; ++r){
        int srow = (r & 3) + 8 * (r >> 2) + 4 * hi;
        if (srow > q5) sv[r] = -1e30f;
      }
    }
    float pm = sv[0];
    #pragma unroll
    for (int r = 1; r < 16; ++r) pm = fmaxf(pm, sv[r]);
    pm = fmaxf(pm, __shfl_xor(pm, 32));
    if (!__all(pm - m <= 8.0f)){   // defer-max (log2 domain)
      float mn = fmaxf(m, pm);
      float al = exp2f(m - mn);
      #pragma unroll
      for (int i = 0; i < 4; ++i) oacc[i] *= al;
      l *= al;
      m = mn;
    }
    float pv[16]; float ts = 0.f;
    #pragma unroll
    for (int r = 0; r < 16; ++r){ pv[r] = exp2f(sv[r] - m); ts += pv[r]; }
    ts += __shfl_xor(ts, 32);
    l += ts;
    // P^T -> bf16 B-frags: cvt_pk + permlane32_swap (fills both k-halves)
    uint32_t w0 = cvt_pk_bf16(pv[0],  pv[1]);
    uint32_t w2 = cvt_pk_bf16(pv[4],  pv[5]);  permswap32(w0, w2);
    uint32_t w1 = cvt_pk_bf16(pv[2],  pv[3]);
    uint32_t w3 = cvt_pk_bf16(pv[6],  pv[7]);  permswap32(w1, w3);
    uint32_t w4 = cvt_pk_bf16(pv[8],  pv[9]);
    uint32_t w6 = cvt_pk_bf16(pv[12], pv[13]); permswap32(w4, w6);
    uint32_t w5 = cvt_pk_bf16(pv[10], pv[11]);
    uint32_t w7 = cvt_pk_bf16(pv[14], pv[15]); permswap32(w5, w7);
    union { uint32_t u[4]; bf16x8 v; } pf0u, pf1u;
    pf0u.u[0] = w0; pf0u.u[1] = w1; pf0u.u[2] = w2; pf0u.u[3] = w3;
    pf1u.u[0] = w4; pf1u.u[1] = w5; pf1u.u[2] = w6; pf1u.u[3] = w7;
    #pragma unroll
    for (int ht = 0; ht < 4; ++ht){   // O^T[h][q] += V^T · P^T
      oacc[ht] = __builtin_amdgcn_mfma_f32_32x32x16_bf16(vf[ht * 2 + 0], pf0u.v, oacc[ht], 0, 0, 0);
      oacc[ht] = __builtin_amdgcn_mfma_f32_32x32x16_bf16(vf[ht * 2 + 1], pf1u.v, oacc[ht], 0, 0, 0);
    }
  }

  // -------- scale-then-sum combine --------
  if (hi == 0){ msh[w][q5] = m; lsh[w][q5] = l; }
  __syncthreads();
  {
    float mv0 = msh[0][q5], mv1 = msh[1][q5], mv2 = msh[2][q5], mv3 = msh[3][q5];
    float lv0 = lsh[0][q5], lv1 = lsh[1][q5], lv2 = lsh[2][q5], lv3 = lsh[3][q5];
    float mfm = fmaxf(fmaxf(mv0, mv1), fmaxf(mv2, mv3));
    float lf  = lv0 * exp2f(mv0 - mfm) + lv1 * exp2f(mv1 - mfm)
              + lv2 * exp2f(mv2 - mfm) + lv3 * exp2f(mv3 - mfm);
    float s = exp2f(m - mfm) / lf;
    #pragma unroll
    for (int ht = 0; ht < 4; ++ht) oacc[ht] *= s;
  }
  // serial RMW accumulate into comb (wave 0 writes, 1..3 add)
  #pragma unroll 1
  for (int rr = 0; rr < 4; ++rr){
    if (w == rr){
      #pragma unroll
      for (int ht = 0; ht < 4; ++ht)
        #pragma unroll
        for (int r4 = 0; r4 < 4; ++r4){
          int hh = ht * 32 + 8 * r4 + 4 * hi;
          float4 add;
          add.x = oacc[ht][r4 * 4 + 0]; add.y = oacc[ht][r4 * 4 + 1];
          add.z = oacc[ht][r4 * 4 + 2]; add.w = oacc[ht][r4 * 4 + 3];
          float* p = &comb[q5][hh];
          if (rr == 0) *(float4*)p = add;
          else { float4 cur = *(const float4*)p;
                 cur.x += add.x; cur.y += add.y; cur.z += add.z; cur.w += add.w;
                 *(float4*)p = cur; }
        }
    }
    __syncthreads();
  }
  // cooperative coalesced store: 32 rows x 128 f32
  float* obase = out + ((size_t)b * 2048 + r0) * 128;
  #pragma unroll
  for (int it = 0; it < 4; ++it){
    int row = it * 8 + (tid >> 5);
    int col = (tid & 31) * 4;
    *(float4*)(obase + row * 128 + col) = *(const float4*)&comb[row][col];
  }
}

extern "C" void kernel_launch(void* const* d_in, const int* in_sizes, int n_in,
                              void* d_out, int out_size, void* d_ws, size_t ws_size,
                              hipStream_t stream){
  const float* x  = (const float*)d_in[0];
  // d_in[1] = mask : causal tril by construction, applied structurally
  const float* Wk = (const float*)d_in[2];
  const float* Wq = (const float*)d_in[3];
  const float* Wv = (const float*)d_in[4];
  char* ws = (char*)d_ws;
  unsigned short* Wt = (unsigned short*)(ws);                    // 768 KB
  unsigned short* Qb = (unsigned short*)(ws + (1ull  << 20));    // 8 MB
  unsigned short* Kb = (unsigned short*)(ws + (9ull  << 20));    // 8 MB
  unsigned short* Vt = (unsigned short*)(ws + (17ull << 20));    // 8 MB
  float* out = (float*)d_out;

  hipLaunchKernelGGL(prep_w,    dim3(1536), dim3(256), 0, stream, Wk, Wq, Wv, Wt);
  hipLaunchKernelGGL(proj_gemm, dim3(768),  dim3(256), 0, stream, x, Wt, Qb, Kb, Vt);
  hipLaunchKernelGGL(attn,      dim3(1024), dim3(256), 0, stream, Qb, Kb, Vt, out);
}

// Round 12
// 103.245 us; speedup vs baseline: 1.1570x; 1.0948x over previous
//
#include <hip/hip_runtime.h>
#include <hip/hip_bf16.h>
#include <stdint.h>

// B=16, T=2048, E=1024, H=128
typedef __attribute__((ext_vector_type(8))) short bf16x8;
typedef __attribute__((ext_vector_type(16))) float f32x16;
typedef __attribute__((ext_vector_type(4))) float f32x4;

__device__ __forceinline__ uint32_t cvt_pk_bf16(float a, float b){
  uint32_t r;
  asm volatile("v_cvt_pk_bf16_f32 %0, %1, %2" : "=v"(r) : "v"(a), "v"(b));
  return r;
}
__device__ __forceinline__ void permswap32(uint32_t &a, uint32_t &b){
  asm volatile("v_permlane32_swap_b32 %0, %1" : "+v"(a), "+v"(b));
}
__device__ __forceinline__ unsigned short f2bf(float f){
  uint32_t u = __float_as_uint(f);
  u += 0x7fff + ((u >> 16) & 1);   // RNE
  return (unsigned short)(u >> 16);
}
__device__ __forceinline__ void gload16(const void* g, void* l){
  __builtin_amdgcn_global_load_lds((const __attribute__((address_space(1))) void*)g,
                                   (__attribute__((address_space(3))) void*)l, 16, 0, 0);
}

// Layouts:
//  Wt lane-linear fragment-major: frag = (k>>5)*24 + (n>>4) (n=mat*128+h, k=e).
//    interior: elem at lane*8 + (k&7), lane = (n&15) + (((k&31)>>3)<<4).
//  QK: elem(b,t,h) -> (b*64 + t/32)*4096 + (h/16)*512 + (t%32)*16 + (h%16)
//  V : elem(b,s,h) -> ((b*64 + s/32)*4 + h/32)*1024 + ((s/16)%2)*512 + (h%32)*16 + (s%16)

// ---------------- Kernel 1: W -> Wt bf16 lane-linear fragment-major
__global__ void prep_w(const float* __restrict__ Wk, const float* __restrict__ Wq,
                       const float* __restrict__ Wv, unsigned short* __restrict__ Wt){
  int idx = blockIdx.x * 256 + threadIdx.x;       // 0 .. 393215  (= dest address)
  int frag = idx >> 9;         // 0..767 = kq*24 + nq
  int r    = idx & 511;
  int ln   = r >> 3;           // lane 0..63
  int j    = r & 7;
  int kq = frag / 24;          // 0..31
  int nq = frag - kq * 24;     // 0..23
  int n  = nq * 16 + (ln & 15);          // 0..383
  int e  = kq * 32 + (ln >> 4) * 8 + j;  // 0..1023
  int mat = n >> 7;
  int h   = n & 127;
  const float* src = (mat == 0) ? Wq : (mat == 1) ? Wk : Wv;
  float v = src[e * 128 + h];
  if (mat == 0) v *= (1.4426950408889634f * 0.08838834764831845f); // log2e/sqrt(128)
  Wt[idx] = f2bf(v);
}

// ---------------- Kernel 2: fused QKV projection GEMM — m97 clone + XCD grouping.
// Tile 128x128, BK=32, grid 768 = 3 blocks/CU; 4 waves x (64x64 = 4x4 acc).
// XCD-grouped bid: the 3 nt-blocks of one mt get launch ids l, l+8, l+16 -> same
// XCD (HW round-robin i%8, m09) -> A-tile fetched from HBM once, hit in L2 twice.
// x HBM traffic 402->134 MB. LDS 24KB single-buffered, all gload16 dests
// wave-uniform 1KB chunks with lane*16B interior; ds_read_b128 conflict-free.
__global__ __launch_bounds__(256, 3) void proj_gemm(
    const float* __restrict__ x, const unsigned short* __restrict__ Wt,
    unsigned short* __restrict__ Qb, unsigned short* __restrict__ Kb,
    unsigned short* __restrict__ Vt){
  __shared__ __align__(16) float          As[8][2][64][4];  // 16 KB
  __shared__ __align__(16) unsigned short Bs[8][64][8];     // 8 KB

  const int tid  = threadIdx.x;
  const int lane = tid & 63;
  const int w    = tid >> 6;            // wave 0..3
  const int wr   = w >> 1;              // row half (64 rows)
  const int wc   = w & 1;               // col half (64 cols)
  const int bid  = blockIdx.x;          // 0..767
  const int grp  = bid / 24;            // 0..31
  const int rem  = bid - grp * 24;
  const int mt   = grp * 8 + (rem & 7); // blocks l, l+8, l+16 share mt AND XCD
  const int nt   = rem >> 3;            // 0..2 -> exactly one of Q/K/V
  const int m0   = mt * 128;

  f32x4 acc[4][4];
  #pragma unroll
  for (int i = 0; i < 4; ++i)
    #pragma unroll
    for (int jj = 0; jj < 4; ++jj) acc[i][jj] = (f32x4){0.f, 0.f, 0.f, 0.f};

  // A staging: wave w stages chunks c=0..3 -> frag f=w*2+(c>>1), half h=c&1.
  const float* aA[4];
  #pragma unroll
  for (int c = 0; c < 4; ++c){
    int f = w * 2 + (c >> 1), h = c & 1;
    aA[c] = x + (size_t)(m0 + f * 16 + (lane & 15)) * 1024 + ((lane >> 4) << 3) + h * 4;
  }
  // B staging: wave w stages frags f=w*2+c (c=0..1); lane sources 16B at frag*512+l*8.
  const unsigned short* bA[2];
  #pragma unroll
  for (int c = 0; c < 2; ++c)
    bA[c] = Wt + ((size_t)(nt * 8 + w * 2 + c) << 9) + (size_t)lane * 8;

  union BU { uint32_t u[4]; bf16x8 v; };

  for (int ks = 0; ks < 32; ++ks){
    // stage current k-slice (6 x gload16 per wave, wave-uniform 1KB dests)
    #pragma unroll
    for (int c = 0; c < 4; ++c)
      gload16(aA[c] + ks * 32, &As[w * 2 + (c >> 1)][c & 1][0][0]);
    #pragma unroll
    for (int c = 0; c < 2; ++c)
      gload16(bA[c] + (size_t)ks * 12288, &Bs[w * 2 + c][0][0]);
    __syncthreads();   // drain vmcnt -> LDS valid

    bf16x8 af[4];
    #pragma unroll
    for (int am = 0; am < 4; ++am){
      float4 lo = *(const float4*)&As[wr * 4 + am][0][lane][0];
      float4 hi = *(const float4*)&As[wr * 4 + am][1][lane][0];
      BU u; u.u[0] = cvt_pk_bf16(lo.x, lo.y); u.u[1] = cvt_pk_bf16(lo.z, lo.w);
            u.u[2] = cvt_pk_bf16(hi.x, hi.y); u.u[3] = cvt_pk_bf16(hi.z, hi.w);
      af[am] = u.v;
    }
    bf16x8 bfr[4];
    #pragma unroll
    for (int bn = 0; bn < 4; ++bn)
      bfr[bn] = *(const bf16x8*)&Bs[wc * 4 + bn][lane][0];
    #pragma unroll
    for (int am = 0; am < 4; ++am)
      #pragma unroll
      for (int bn = 0; bn < 4; ++bn)
        acc[am][bn] = __builtin_amdgcn_mfma_f32_16x16x32_bf16(af[am], bfr[bn], acc[am][bn], 0, 0, 0);
    __syncthreads();   // reads done before next stage overwrites
  }

  const int b  = m0 >> 11;
  const int t0 = m0 & 2047;
  const int lr = lane & 15;
  const int lk = lane >> 4;
  #pragma unroll
  for (int am = 0; am < 4; ++am){
    #pragma unroll
    for (int bn = 0; bn < 4; ++bn){
      int hcol = wc * 64 + bn * 16 + lr;            // 0..127 within matrix nt
      int tr   = t0 + wr * 64 + am * 16 + lk * 4;   // D: row=(lane>>4)*4+j, col=lane&15
      f32x4 v = acc[am][bn];
      if (nt <= 1){
        unsigned short* dst = (nt == 0) ? Qb : Kb;
        size_t base = (size_t)(b * 64 + (tr >> 5)) * 4096 + (size_t)(hcol >> 4) * 512 + (hcol & 15);
        #pragma unroll
        for (int jj = 0; jj < 4; ++jj)
          dst[base + (size_t)((tr + jj) & 31) * 16] = f2bf(v[jj]);
      } else { // V fragment-major: 4 consecutive s -> 8B store
        ushort4 pk;
        pk.x = f2bf(v[0]); pk.y = f2bf(v[1]); pk.z = f2bf(v[2]); pk.w = f2bf(v[3]);
        size_t addr = (size_t)((b * 64 + (tr >> 5)) * 4 + (hcol >> 5)) * 1024
                    + (size_t)((tr >> 4) & 1) * 512 + (size_t)(hcol & 31) * 16 + (tr & 15);
        *(ushort4*)(Vt + addr) = pk;
      }
    }
  }
}

// ---------------- Kernel 3: causal flash attention, swapped-QK 32x32x16.
// 1024 blocks, 4 waves = 4-way kv split, scale-then-sum combine (17.9KB LDS).
__global__ __launch_bounds__(256, 2) void attn(
    const unsigned short* __restrict__ Qf, const unsigned short* __restrict__ Kf,
    const unsigned short* __restrict__ Vf, float* __restrict__ out){
  __shared__ float comb[32][132];
  __shared__ float msh[4][32];
  __shared__ float lsh[4][32];

  const int tid  = threadIdx.x;
  const int lane = tid & 63;
  const int w    = tid >> 6;            // kv-split index 0..3
  const int bid  = blockIdx.x;
  const int xcd  = bid & 7;
  const int k    = bid >> 3;            // 0..127 within XCD
  const int a    = k & 31;
  const int mdx  = k >> 5;              // 0..3
  const int b    = xcd * 2 + (mdx >> 1);
  const int c    = (mdx & 1) ? a : 63 - a;   // per-CU sets {63-a, a} x 2 batches
  const int r0   = c * 32;
  const int q5   = lane & 31;
  const int hi   = lane >> 5;

  bf16x8 qf[8];
  const unsigned short* qp = Qf + (size_t)(b * 64 + c) * 4096 + q5 * 16 + hi * 8;
  #pragma unroll
  for (int f = 0; f < 8; ++f) qf[f] = *(const bf16x8*)(qp + f * 512);

  f32x16 oacc[4];
  #pragma unroll
  for (int i = 0; i < 4; ++i) oacc[i] = (f32x16)(0.f);
  float m = -1e30f, l = 0.f;

  const unsigned short* kb = Kf + (size_t)b * 64 * 4096;
  const unsigned short* vb = Vf + (size_t)b * 64 * 4096;

  bf16x8 kf[8];
  if (w <= c){
    const unsigned short* kp = kb + (size_t)w * 4096 + q5 * 16 + hi * 8;
    #pragma unroll
    for (int f = 0; f < 8; ++f) kf[f] = *(const bf16x8*)(kp + f * 512);
  }

  for (int t = w; t <= c; t += 4){
    f32x16 sacc = (f32x16)(0.f);   // S^T[s][q] = sum_h K[s][h] Q[q][h]
    #pragma unroll
    for (int f = 0; f < 8; ++f)
      sacc = __builtin_amdgcn_mfma_f32_32x32x16_bf16(kf[f], qf[f], sacc, 0, 0, 0);
    // prefetch next K tile (overlaps softmax+PV)
    if (t + 4 <= c){
      const unsigned short* kp = kb + (size_t)(t + 4) * 4096 + q5 * 16 + hi * 8;
      #pragma unroll
      for (int f = 0; f < 8; ++f) kf[f] = *(const bf16x8*)(kp + f * 512);
    }
    // V fragments (contiguous 1KB per instr), issued before softmax
    bf16x8 vf[8];
    const unsigned short* vp = vb + (size_t)t * 4096 + q5 * 16 + hi * 8;
    #pragma unroll
    for (int ht = 0; ht < 4; ++ht)
      #pragma unroll
      for (int sf = 0; sf < 2; ++sf)
        vf[ht * 2 + sf] = *(const bf16x8*)(vp + ht * 1024 + sf * 512);

    float sv[16];
    #pragma unroll
    for (int r = 0; r < 16; ++r) sv[r] = sacc[r];
    if (t == c){   // diagonal tile: mask s>q  (row = (r&3)+8*(r>>2)+4*hi, col q = q5)
      #pragma unroll
      for (int r = 0; r < 16; ++r){
        int srow = (r & 3) + 8 * (r >> 2) + 4 * hi;
        if (srow > q5) sv[r] = -1e30f;
      }
    }
    float pm = sv[0];
    #pragma unroll
    for (int r = 1; r < 16; ++r) pm = fmaxf(pm, sv[r]);
    pm = fmaxf(pm, __shfl_xor(pm, 32));
    if (!__all(pm - m <= 8.0f)){   // defer-max (log2 domain)
      float mn = fmaxf(m, pm);
      float al = exp2f(m - mn);
      #pragma unroll
      for (int i = 0; i < 4; ++i) oacc[i] *= al;
      l *= al;
      m = mn;
    }
    float pv[16]; float ts = 0.f;
    #pragma unroll
    for (int r = 0; r < 16; ++r){ pv[r] = exp2f(sv[r] - m); ts += pv[r]; }
    ts += __shfl_xor(ts, 32);
    l += ts;
    // P^T -> bf16 B-frags: cvt_pk + permlane32_swap (fills both k-halves)
    uint32_t w0 = cvt_pk_bf16(pv[0],  pv[1]);
    uint32_t w2 = cvt_pk_bf16(pv[4],  pv[5]);  permswap32(w0, w2);
    uint32_t w1 = cvt_pk_bf16(pv[2],  pv[3]);
    uint32_t w3 = cvt_pk_bf16(pv[6],  pv[7]);  permswap32(w1, w3);
    uint32_t w4 = cvt_pk_bf16(pv[8],  pv[9]);
    uint32_t w6 = cvt_pk_bf16(pv[12], pv[13]); permswap32(w4, w6);
    uint32_t w5 = cvt_pk_bf16(pv[10], pv[11]);
    uint32_t w7 = cvt_pk_bf16(pv[14], pv[15]); permswap32(w5, w7);
    union { uint32_t u[4]; bf16x8 v; } pf0u, pf1u;
    pf0u.u[0] = w0; pf0u.u[1] = w1; pf0u.u[2] = w2; pf0u.u[3] = w3;
    pf1u.u[0] = w4; pf1u.u[1] = w5; pf1u.u[2] = w6; pf1u.u[3] = w7;
    #pragma unroll
    for (int ht = 0; ht < 4; ++ht){   // O^T[h][q] += V^T · P^T
      oacc[ht] = __builtin_amdgcn_mfma_f32_32x32x16_bf16(vf[ht * 2 + 0], pf0u.v, oacc[ht], 0, 0, 0);
      oacc[ht] = __builtin_amdgcn_mfma_f32_32x32x16_bf16(vf[ht * 2 + 1], pf1u.v, oacc[ht], 0, 0, 0);
    }
  }

  // -------- scale-then-sum combine --------
  if (hi == 0){ msh[w][q5] = m; lsh[w][q5] = l; }
  __syncthreads();
  {
    float mv0 = msh[0][q5], mv1 = msh[1][q5], mv2 = msh[2][q5], mv3 = msh[3][q5];
    float lv0 = lsh[0][q5], lv1 = lsh[1][q5], lv2 = lsh[2][q5], lv3 = lsh[3][q5];
    float mfm = fmaxf(fmaxf(mv0, mv1), fmaxf(mv2, mv3));
    float lf  = lv0 * exp2f(mv0 - mfm) + lv1 * exp2f(mv1 - mfm)
              + lv2 * exp2f(mv2 - mfm) + lv3 * exp2f(mv3 - mfm);
    float s = exp2f(m - mfm) / lf;
    #pragma unroll
    for (int ht = 0; ht < 4; ++ht) oacc[ht] *= s;
  }
  // serial RMW accumulate into comb (wave 0 writes, 1..3 add)
  #pragma unroll 1
  for (int rr = 0; rr < 4; ++rr){
    if (w == rr){
      #pragma unroll
      for (int ht = 0; ht < 4; ++ht)
        #pragma unroll
        for (int r4 = 0; r4 < 4; ++r4){
          int hh = ht * 32 + 8 * r4 + 4 * hi;
          float4 add;
          add.x = oacc[ht][r4 * 4 + 0]; add.y = oacc[ht][r4 * 4 + 1];
          add.z = oacc[ht][r4 * 4 + 2]; add.w = oacc[ht][r4 * 4 + 3];
          float* p = &comb[q5][hh];
          if (rr == 0) *(float4*)p = add;
          else { float4 cur = *(const float4*)p;
                 cur.x += add.x; cur.y += add.y; cur.z += add.z; cur.w += add.w;
                 *(float4*)p = cur; }
        }
    }
    __syncthreads();
  }
  // cooperative coalesced store: 32 rows x 128 f32
  float* obase = out + ((size_t)b * 2048 + r0) * 128;
  #pragma unroll
  for (int it = 0; it < 4; ++it){
    int row = it * 8 + (tid >> 5);
    int col = (tid & 31) * 4;
    *(float4*)(obase + row * 128 + col) = *(const float4*)&comb[row][col];
  }
}

extern "C" void kernel_launch(void* const* d_in, const int* in_sizes, int n_in,
                              void* d_out, int out_size, void* d_ws, size_t ws_size,
                              hipStream_t stream){
  const float* x  = (const float*)d_in[0];
  // d_in[1] = mask : causal tril by construction, applied structurally
  const float* Wk = (const float*)d_in[2];
  const float* Wq = (const float*)d_in[3];
  const float* Wv = (const float*)d_in[4];
  char* ws = (char*)d_ws;
  unsigned short* Wt = (unsigned short*)(ws);                    // 768 KB
  unsigned short* Qb = (unsigned short*)(ws + (1ull  << 20));    // 8 MB
  unsigned short* Kb = (unsigned short*)(ws + (9ull  << 20));    // 8 MB
  unsigned short* Vt = (unsigned short*)(ws + (17ull << 20));    // 8 MB
  float* out = (float*)d_out;

  hipLaunchKernelGGL(prep_w,    dim3(1536), dim3(256), 0, stream, Wk, Wq, Wv, Wt);
  hipLaunchKernelGGL(proj_gemm, dim3(768),  dim3(256), 0, stream, x, Wt, Qb, Kb, Vt);
  hipLaunchKernelGGL(attn,      dim3(1024), dim3(256), 0, stream, Qb, Kb, Vt, out);
}